// Round 8
// baseline (25092.451 us; speedup 1.0000x reference)
//
#include <hip/hip_runtime.h>
#include <stdint.h>

#define NB 64
#define NT 2048
#define ND 1024
#define NU 1024
#define FLAG_STRIDE 16  // flags 64B apart -> no shared-line convoy

typedef __attribute__((ext_vector_type(8))) short bf16x8;
typedef __attribute__((ext_vector_type(4))) float f32x4;
typedef __attribute__((ext_vector_type(4))) unsigned u32x4;

__device__ __forceinline__ unsigned short f2bf(float f) {
  union { float f; unsigned u; } v; v.f = f;
  return (unsigned short)((v.u + 0x7FFFu + ((v.u >> 16) & 1u)) >> 16);
}

// ---------------- init: winner=~0, tickets/flags=0, h double-buffer=0 ----------------
// ws words: [0] sticky winner, [16..31] tickets[chunk], [256..511] flags,
//           [1024..66559] h double-buffer (2 x 64x1024 bf16)
__global__ void init_ws(unsigned* __restrict__ ws) {
  const int n = 1024 + (2 * NB * NU) / 2;
  for (int i = blockIdx.x * blockDim.x + threadIdx.x; i < n; i += gridDim.x * blockDim.x)
    ws[i] = (i == 0) ? 0xFFFFFFFFu : 0u;
}

// ---------------- xp = inputs @ W_x + b  (bf16 MFMA, 128x128 tile) ----------------
__launch_bounds__(256, 3)
__global__ void gemm_xp(const float* __restrict__ inp, const float* __restrict__ Wx,
                        const float* __restrict__ bias, float* __restrict__ xp,
                        int t0, int Tc) {
  __shared__ unsigned short As[128][56];
  __shared__ unsigned short Bs[128][56];

  const int tid = threadIdx.x;
  const int u0 = blockIdx.x * 128;
  const int m_base = blockIdx.y * 128;
  const int b = m_base / Tc;
  const int tc0 = m_base % Tc;
  const size_t arow0 = ((size_t)b * NT + t0 + tc0) * (size_t)ND;

  const int w = tid >> 6, lane = tid & 63;
  const int wr = w >> 1, wc = w & 1;
  const int l15 = lane & 15, lk = lane >> 4;
  const int srow = tid & 127;
  const int shalf = tid >> 7;

  f32x4 acc[4][4];
  #pragma unroll
  for (int i = 0; i < 4; ++i)
    #pragma unroll
    for (int j = 0; j < 4; ++j)
      acc[i][j] = (f32x4){0.f, 0.f, 0.f, 0.f};

  for (int k0 = 0; k0 < ND; k0 += 32) {
    __syncthreads();
    {
      const float* src = inp + arow0 + (size_t)srow * ND + k0 + shalf * 16;
      unsigned short tmp[16];
      #pragma unroll
      for (int i = 0; i < 16; i += 4) {
        float4 v = *(const float4*)(src + i);
        tmp[i + 0] = f2bf(v.x); tmp[i + 1] = f2bf(v.y);
        tmp[i + 2] = f2bf(v.z); tmp[i + 3] = f2bf(v.w);
      }
      #pragma unroll
      for (int h = 0; h < 2; ++h) {
        bf16x8 pv;
        #pragma unroll
        for (int j = 0; j < 8; ++j) pv[j] = (short)tmp[h * 8 + j];
        *(bf16x8*)&As[srow][shalf * 16 + h * 8] = pv;
      }
    }
    {
      const float* src = Wx + (size_t)(k0 + shalf * 16) * NU + u0 + srow;
      unsigned short tmp[16];
      #pragma unroll
      for (int i = 0; i < 16; ++i) tmp[i] = f2bf(src[(size_t)i * NU]);
      #pragma unroll
      for (int h = 0; h < 2; ++h) {
        bf16x8 pv;
        #pragma unroll
        for (int j = 0; j < 8; ++j) pv[j] = (short)tmp[h * 8 + j];
        *(bf16x8*)&Bs[srow][shalf * 16 + h * 8] = pv;
      }
    }
    __syncthreads();

    bf16x8 af[4], bfr[4];
    #pragma unroll
    for (int mf = 0; mf < 4; ++mf)
      af[mf] = *(const bf16x8*)&As[wr * 64 + mf * 16 + l15][lk * 8];
    #pragma unroll
    for (int nf = 0; nf < 4; ++nf)
      bfr[nf] = *(const bf16x8*)&Bs[wc * 64 + nf * 16 + l15][lk * 8];
    #pragma unroll
    for (int mf = 0; mf < 4; ++mf)
      #pragma unroll
      for (int nf = 0; nf < 4; ++nf)
        acc[mf][nf] = __builtin_amdgcn_mfma_f32_16x16x32_bf16(af[mf], bfr[nf], acc[mf][nf], 0, 0, 0);
  }

  #pragma unroll
  for (int nf = 0; nf < 4; ++nf) {
    const int col = u0 + wc * 64 + nf * 16 + l15;
    const float bv = bias[col];
    #pragma unroll
    for (int mf = 0; mf < 4; ++mf) {
      const int rbase = m_base + wr * 64 + mf * 16 + lk * 4;
      #pragma unroll
      for (int r = 0; r < 4; ++r)
        xp[(size_t)(rbase + r) * NU + col] = acc[mf][nf][r] + bv;
    }
  }
}

// ---------------- persistent recurrent scan: single-XCD workers, L2-local h ----------------
// 256 WGs launched; hang-free election: one CAS on sticky winner, per-chunk tickets,
// first 16 WGs on the winner XCD become workers (wid=ticket), others exit immediately.
// Flags: agent scope (proven round-6 protocol). h data: plain write-through stores into
// the winner XCD's L2; consumers do buffer_inv sc1 (agent-acquire primitive) then plain
// dwordx4 loads -> local L2 hits instead of fabric round-trips.
__launch_bounds__(512, 1)
__global__ void scan_kernel(const float* __restrict__ Wh, const float* __restrict__ xp,
                            unsigned short* __restrict__ hbuf, float* __restrict__ out,
                            unsigned* __restrict__ ws, int t0, int Tc, int chunk) {
  __shared__ float Red[4][2][64][36];  // [k4][m2][col][row(+pad)] f32 partials (72 KB)
  __shared__ unsigned s_tk;

  const int tid = threadIdx.x;
  unsigned xcc;
  asm volatile("s_getreg_b32 %0, hwreg(HW_REG_XCC_ID)" : "=s"(xcc));

  unsigned* winner  = ws;        // [0] sticky across chunks (init once per launch)
  unsigned* tickets = ws + 16;   // [chunk]
  unsigned* flags   = ws + 256;  // [16] * FLAG_STRIDE

  // ---- hang-free election: no spin anywhere ----
  if (tid == 0) {
    unsigned exp = 0xFFFFFFFFu;
    __hip_atomic_compare_exchange_strong(winner, &exp, xcc,
        __ATOMIC_RELAXED, __ATOMIC_RELAXED, __HIP_MEMORY_SCOPE_AGENT);
    const unsigned wv = __hip_atomic_load(winner, __ATOMIC_RELAXED, __HIP_MEMORY_SCOPE_AGENT);
    unsigned tk = 0xFFFFu;
    if (wv == xcc)
      tk = __hip_atomic_fetch_add(&tickets[chunk], 1u,
                                  __ATOMIC_RELAXED, __HIP_MEMORY_SCOPE_AGENT);
    s_tk = tk;
  }
  __syncthreads();
  if (s_tk >= 16u) return;      // not a worker
  const int wid = (int)s_tk;    // 0..15

  const int col0 = wid * 64;
  const int lane = tid & 63;
  const int w = tid >> 6;       // 0..7
  const int k4 = w & 3;         // K-quarter: k in [k4*256, +256)
  const int m2 = w >> 2;        // M-half: rows [m2*32, +32)
  const int l15 = lane & 15;
  const int lk = lane >> 4;

  // ---- persistent W_h B-fragments: Bf[nf][kq] = 128 VGPR ----
  bf16x8 Bf[4][8];
  for (int nf = 0; nf < 4; ++nf)
    for (int kq = 0; kq < 8; ++kq) {
      const int col = col0 + nf * 16 + l15;
      bf16x8 v;
      #pragma unroll
      for (int j = 0; j < 8; ++j) {
        const int k = (k4 * 8 + kq) * 32 + lk * 8 + j;
        v[j] = (short)f2bf(Wh[(size_t)k * NU + col]);
      }
      Bf[nf][kq] = v;
    }

  // reduce/store mapping: thread -> (1 col, 8 rows)
  const int rcol = tid & 63;
  const int rgrp = tid >> 6;        // 0..7
  const int rrow = rgrp * 8;
  const int rm = rgrp >> 2;         // m-half
  const int rlm = (rgrp & 3) * 8;   // row base within half

  const unsigned* fpoll = flags + (size_t)(k4 * 4 + (lane & 3)) * FLAG_STRIDE;
  unsigned* fown = flags + (size_t)wid * FLAG_STRIDE;

  for (int tc = 0; tc < Tc; ++tc) {
    const int t = t0 + tc;
    const unsigned short* hc = hbuf + (size_t)(t & 1) * (NB * NU);
    unsigned short* hn = hbuf + (size_t)((t + 1) & 1) * (NB * NU);

    // xp prefetch (independent of h) before the poll
    float xpv[8];
    #pragma unroll
    for (int r = 0; r < 8; ++r)
      xpv[r] = xp[((size_t)(rrow + r) * Tc + tc) * NU + col0 + rcol];

    f32x4 acc[2][4];
    #pragma unroll
    for (int mf = 0; mf < 2; ++mf)
      #pragma unroll
      for (int nf = 0; nf < 4; ++nf)
        acc[mf][nf] = (f32x4){0.f, 0.f, 0.f, 0.f};

    if (t != 0) {  // t==0: h_0 == 0 -> acc stays 0, no poll, no loads
      // ---- poll 4 producer flags of this wave's K-quarter (agent scope, proven) ----
      const unsigned tgt = (unsigned)t;
      for (;;) {
        unsigned fv = tgt;
        if (lane < 4)
          fv = __hip_atomic_load(fpoll, __ATOMIC_RELAXED, __HIP_MEMORY_SCOPE_AGENT);
        if (__all((int)(fv >= tgt))) break;
        __builtin_amdgcn_s_sleep(1);
      }
      // agent-acquire primitive: drop stale clean L1/L2 lines (keeps dirty h lines),
      // then plain loads below hit the winner XCD's L2 at local latency.
      asm volatile("buffer_inv sc1\n\ts_waitcnt vmcnt(0)" ::: "memory");
      __builtin_amdgcn_sched_barrier(0);

      // ---- MFMA: A (h_t) via plain dwordx4 loads (local L2 hits), B from VGPRs ----
      u32x4 av[16];
      #pragma unroll
      for (int kq = 0; kq < 8; ++kq)
        #pragma unroll
        for (int mf = 0; mf < 2; ++mf)
          av[kq * 2 + mf] = *(const u32x4*)(hc + (size_t)(m2 * 32 + mf * 16 + l15) * NU +
                                            (k4 * 8 + kq) * 32 + lk * 8);
      #pragma unroll
      for (int kq = 0; kq < 8; ++kq)
        #pragma unroll
        for (int mf = 0; mf < 2; ++mf) {
          union { u32x4 u; bf16x8 v; } a; a.u = av[kq * 2 + mf];
          #pragma unroll
          for (int nf = 0; nf < 4; ++nf)
            acc[mf][nf] = __builtin_amdgcn_mfma_f32_16x16x32_bf16(
                a.v, Bf[nf][kq], acc[mf][nf], 0, 0, 0);
        }
    }

    // write K-partials
    #pragma unroll
    for (int mf = 0; mf < 2; ++mf)
      #pragma unroll
      for (int nf = 0; nf < 4; ++nf)
        *(f32x4*)&Red[k4][m2][nf * 16 + l15][mf * 16 + lk * 4] = acc[mf][nf];
    __syncthreads();  // partials visible (also guards Red reuse)

    // ---- reduce + xp + tanh -> packed u32 stores (write-through into local L2) ----
    {
      f32x4 sa = *(const f32x4*)&Red[0][rm][rcol][rlm];
      f32x4 sb = *(const f32x4*)&Red[0][rm][rcol][rlm + 4];
      #pragma unroll
      for (int q = 1; q < 4; ++q) {
        sa += *(const f32x4*)&Red[q][rm][rcol][rlm];
        sb += *(const f32x4*)&Red[q][rm][rcol][rlm + 4];
      }
      #pragma unroll
      for (int r = 0; r < 4; ++r) {
        const float z = sa[r] + xpv[r];
        const float e = __expf(2.0f * z);
        const float hv = 1.0f - 2.0f / (e + 1.0f);   // tanh(z)
        if (t == NT - 1) out[(size_t)(rrow + r) * NU + col0 + rcol] = hv;
        const unsigned mybf = f2bf(hv);
        const unsigned nb = (unsigned)__shfl_xor((int)mybf, 1);
        if (!(lane & 1))
          __hip_atomic_store((unsigned*)(hn + (size_t)(rrow + r) * NU + col0 + rcol),
                             mybf | (nb << 16), __ATOMIC_RELAXED, __HIP_MEMORY_SCOPE_WORKGROUP);
      }
      #pragma unroll
      for (int r = 0; r < 4; ++r) {
        const float z = sb[r] + xpv[r + 4];
        const float e = __expf(2.0f * z);
        const float hv = 1.0f - 2.0f / (e + 1.0f);
        if (t == NT - 1) out[(size_t)(rrow + 4 + r) * NU + col0 + rcol] = hv;
        const unsigned mybf = f2bf(hv);
        const unsigned nb = (unsigned)__shfl_xor((int)mybf, 1);
        if (!(lane & 1))
          __hip_atomic_store((unsigned*)(hn + (size_t)(rrow + 4 + r) * NU + col0 + rcol),
                             mybf | (nb << 16), __ATOMIC_RELAXED, __HIP_MEMORY_SCOPE_WORKGROUP);
      }
    }
    __syncthreads();  // vmcnt(0) drain in every wave: all h stores ACKed at L2

    if (tid == 0)     // agent flag store (relaxed; data already at/behind the L2)
      __hip_atomic_store(fown, (unsigned)(t + 1), __ATOMIC_RELAXED, __HIP_MEMORY_SCOPE_AGENT);
  }
}

extern "C" void kernel_launch(void* const* d_in, const int* in_sizes, int n_in,
                              void* d_out, int out_size, void* d_ws, size_t ws_size,
                              hipStream_t stream) {
  (void)in_sizes; (void)n_in; (void)out_size;
  const float* inp  = (const float*)d_in[0];
  const float* Wx   = (const float*)d_in[1];
  const float* Wh   = (const float*)d_in[2];
  const float* bias = (const float*)d_in[3];
  float* out = (float*)d_out;

  unsigned* ws = (unsigned*)d_ws;                                  // 4 KB control area
  unsigned short* hbuf = (unsigned short*)((char*)d_ws + 4096);    // 256 KB h double-buffer
  const size_t xp_off = 4096 + (size_t)2 * NB * NU * sizeof(unsigned short);
  float* xp = (float*)((char*)d_ws + xp_off);
  const size_t avail = (ws_size > xp_off) ? ws_size - xp_off : 0;

  int Tc = 128;
  for (int cand = NT; cand >= 128; cand >>= 1)
    if ((size_t)NB * (size_t)cand * NU * sizeof(float) <= avail) { Tc = cand; break; }

  init_ws<<<dim3(128), dim3(256), 0, stream>>>(ws);

  for (int t0 = 0; t0 < NT; t0 += Tc) {
    gemm_xp<<<dim3(8, (NB * Tc) / 128), dim3(256), 0, stream>>>(inp, Wx, bias, xp, t0, Tc);
    scan_kernel<<<dim3(256), dim3(512), 0, stream>>>(Wh, xp, hbuf, out, ws, t0, Tc, t0 / Tc);
  }
}

// Round 10
// 12997.444 us; speedup vs baseline: 1.9306x; 1.9306x over previous
//
#include <hip/hip_runtime.h>
#include <stdint.h>

#define NB 64
#define NT 2048
#define ND 1024
#define NU 1024
#define RETRY_MAX (1 << 20)

typedef __attribute__((ext_vector_type(8))) short bf16x8;
typedef __attribute__((ext_vector_type(4))) float f32x4;
typedef unsigned long long u64;

__device__ __forceinline__ unsigned short f2bf(float f) {
  union { float f; unsigned u; } v; v.f = f;
  return (unsigned short)((v.u + 0x7FFFu + ((v.u >> 16) & 1u)) >> 16);
}

// ---------------- init: slots=~0, tickets=0, tagged h double-buffer=0 ----------------
// ws words: [0..3] cluster slots (XCD ids), [16..79] tickets[slot*16+chunk],
//           [1024..132095] tagged h double-buffer (2 x 64x1024 u32)
__global__ void init_ws(unsigned* __restrict__ ws) {
  const int n = 1024 + 2 * NB * NU;
  for (int i = blockIdx.x * blockDim.x + threadIdx.x; i < n; i += gridDim.x * blockDim.x)
    ws[i] = (i < 4) ? 0xFFFFFFFFu : 0u;
}

// ---------------- xp = inputs @ W_x + b  (bf16 MFMA, 128x128 tile) ----------------
__launch_bounds__(256, 3)
__global__ void gemm_xp(const float* __restrict__ inp, const float* __restrict__ Wx,
                        const float* __restrict__ bias, float* __restrict__ xp,
                        int t0, int Tc) {
  __shared__ unsigned short As[128][56];
  __shared__ unsigned short Bs[128][56];

  const int tid = threadIdx.x;
  const int u0 = blockIdx.x * 128;
  const int m_base = blockIdx.y * 128;
  const int b = m_base / Tc;
  const int tc0 = m_base % Tc;
  const size_t arow0 = ((size_t)b * NT + t0 + tc0) * (size_t)ND;

  const int w = tid >> 6, lane = tid & 63;
  const int wr = w >> 1, wc = w & 1;
  const int l15 = lane & 15, lk = lane >> 4;
  const int srow = tid & 127;
  const int shalf = tid >> 7;

  f32x4 acc[4][4];
  #pragma unroll
  for (int i = 0; i < 4; ++i)
    #pragma unroll
    for (int j = 0; j < 4; ++j)
      acc[i][j] = (f32x4){0.f, 0.f, 0.f, 0.f};

  for (int k0 = 0; k0 < ND; k0 += 32) {
    __syncthreads();
    {
      const float* src = inp + arow0 + (size_t)srow * ND + k0 + shalf * 16;
      unsigned short tmp[16];
      #pragma unroll
      for (int i = 0; i < 16; i += 4) {
        float4 v = *(const float4*)(src + i);
        tmp[i + 0] = f2bf(v.x); tmp[i + 1] = f2bf(v.y);
        tmp[i + 2] = f2bf(v.z); tmp[i + 3] = f2bf(v.w);
      }
      #pragma unroll
      for (int h = 0; h < 2; ++h) {
        bf16x8 pv;
        #pragma unroll
        for (int j = 0; j < 8; ++j) pv[j] = (short)tmp[h * 8 + j];
        *(bf16x8*)&As[srow][shalf * 16 + h * 8] = pv;
      }
    }
    {
      const float* src = Wx + (size_t)(k0 + shalf * 16) * NU + u0 + srow;
      unsigned short tmp[16];
      #pragma unroll
      for (int i = 0; i < 16; ++i) tmp[i] = f2bf(src[(size_t)i * NU]);
      #pragma unroll
      for (int h = 0; h < 2; ++h) {
        bf16x8 pv;
        #pragma unroll
        for (int j = 0; j < 8; ++j) pv[j] = (short)tmp[h * 8 + j];
        *(bf16x8*)&Bs[srow][shalf * 16 + h * 8] = pv;
      }
    }
    __syncthreads();

    bf16x8 af[4], bfr[4];
    #pragma unroll
    for (int mf = 0; mf < 4; ++mf)
      af[mf] = *(const bf16x8*)&As[wr * 64 + mf * 16 + l15][lk * 8];
    #pragma unroll
    for (int nf = 0; nf < 4; ++nf)
      bfr[nf] = *(const bf16x8*)&Bs[wc * 64 + nf * 16 + l15][lk * 8];
    #pragma unroll
    for (int mf = 0; mf < 4; ++mf)
      #pragma unroll
      for (int nf = 0; nf < 4; ++nf)
        acc[mf][nf] = __builtin_amdgcn_mfma_f32_16x16x32_bf16(af[mf], bfr[nf], acc[mf][nf], 0, 0, 0);
  }

  #pragma unroll
  for (int nf = 0; nf < 4; ++nf) {
    const int col = u0 + wc * 64 + nf * 16 + l15;
    const float bv = bias[col];
    #pragma unroll
    for (int mf = 0; mf < 4; ++mf) {
      const int rbase = m_base + wr * 64 + mf * 16 + lk * 4;
      #pragma unroll
      for (int r = 0; r < 4; ++r)
        xp[(size_t)(rbase + r) * NU + col] = acc[mf][nf][r] + bv;
    }
  }
}

// ---------------- persistent scan: 4 clusters, tag-in-data, AGENT-scope primitives ----------------
// 256 WGs x 512 thr. Hang-free 4-slot CAS election pins each cluster to one XCD.
// Cluster c owns batch rows [c*16,+16); its 16 WGs own 64 cols each; wave = K-eighth.
// h element = u32 (tag<<16 | bf16), stored as u64 col-pairs via relaxed AGENT stores
// (write-through -> guaranteed visible); consumers retry relaxed AGENT u64 loads until
// all 16 embedded tags >= t. No flags, no barriers between WGs, no RELEASE, no sc0 asm.
__launch_bounds__(512, 1)
__global__ void scan_kernel(const float* __restrict__ Wh, const float* __restrict__ xp,
                            unsigned* __restrict__ hw, float* __restrict__ out,
                            unsigned* __restrict__ ws, int t0, int Tc, int chunk) {
  __shared__ float Red[8][64][20];  // [k8][col][row(+pad)] f32 partials (40 KB)
  __shared__ unsigned s_slot, s_tk;

  const int tid = threadIdx.x;
  unsigned xcc;
  asm volatile("s_getreg_b32 %0, hwreg(HW_REG_XCC_ID)" : "=s"(xcc));

  unsigned* slots   = ws;        // [0..3]
  unsigned* tickets = ws + 16;   // [slot*16 + chunk]

  // ---- hang-free 4-slot election (each slot = one XCD = one cluster) ----
  if (tid == 0) {
    unsigned slot = 0xFFFFFFFFu;
    #pragma unroll
    for (int s = 0; s < 4; ++s) {
      unsigned exp = 0xFFFFFFFFu;
      __hip_atomic_compare_exchange_strong(&slots[s], &exp, xcc,
          __ATOMIC_RELAXED, __ATOMIC_RELAXED, __HIP_MEMORY_SCOPE_AGENT);
      const unsigned v = __hip_atomic_load(&slots[s], __ATOMIC_RELAXED, __HIP_MEMORY_SCOPE_AGENT);
      if (v == xcc) { slot = (unsigned)s; break; }
    }
    unsigned tk = 0xFFFFu;
    if (slot <= 3u)
      tk = __hip_atomic_fetch_add(&tickets[slot * 16 + chunk], 1u,
                                  __ATOMIC_RELAXED, __HIP_MEMORY_SCOPE_AGENT);
    s_slot = slot; s_tk = tk;
  }
  __syncthreads();
  if (s_slot > 3u || s_tk >= 16u) return;  // not a worker
  const int cluster = (int)s_slot;         // batch rows [cluster*16, +16)
  const int j = (int)s_tk;                 // WG owns cols [j*64, +64)

  const int r0 = cluster * 16;
  const int gc0 = j * 64;
  const int lane = tid & 63;
  const int k8 = tid >> 6;      // wave = K-eighth [k8*128, +128)
  const int l15 = lane & 15;
  const int lk = lane >> 4;

  // ---- persistent W_h B-fragments: Bf[nf 0..3][kq 0..3] = 64 VGPR ----
  bf16x8 Bf[4][4];
  for (int nf = 0; nf < 4; ++nf)
    for (int kq = 0; kq < 4; ++kq) {
      const int col = gc0 + nf * 16 + l15;
      bf16x8 v;
      #pragma unroll
      for (int jj = 0; jj < 8; ++jj) {
        const int k = k8 * 128 + kq * 32 + lk * 8 + jj;
        v[jj] = (short)f2bf(Wh[(size_t)k * NU + col]);
      }
      Bf[nf][kq] = v;
    }

  // reduce/store mapping: thread -> (1 col, 2 rows)
  const int rcol = tid & 63;          // local col
  const int rg = tid >> 6;            // 0..7 -> rows rg*2, rg*2+1
  const int gcol = gc0 + rcol;

  for (int tc = 0; tc < Tc; ++tc) {
    const int t = t0 + tc;
    const unsigned* hc = hw + (size_t)(t & 1) * (NB * NU);
    unsigned* hn = hw + (size_t)((t + 1) & 1) * (NB * NU);
    const unsigned tagn = ((unsigned)(t + 1)) << 16;

    // xp prefetch (independent of h)
    float xpv[2];
    #pragma unroll
    for (int r = 0; r < 2; ++r)
      xpv[r] = xp[((size_t)(r0 + rg * 2 + r) * Tc + tc) * NU + gcol];

    f32x4 acc[4];
    #pragma unroll
    for (int nf = 0; nf < 4; ++nf) acc[nf] = (f32x4){0.f, 0.f, 0.f, 0.f};

    if (t != 0) {  // t==0: h_0 == 0 -> acc stays 0
      // ---- tagged A-load retry: relaxed AGENT u64 loads until all tags >= t ----
      u64 wv[16];  // [kq*4 + q] : q-th col-pair of k-block kq
      const unsigned* pb = hc + (size_t)(r0 + l15) * NU + k8 * 128 + lk * 8;
      const unsigned tgt = (unsigned)t;
      for (int it = 0; it < RETRY_MAX; ++it) {
        #pragma unroll
        for (int kq = 0; kq < 4; ++kq)
          #pragma unroll
          for (int q = 0; q < 4; ++q)
            wv[kq * 4 + q] = __hip_atomic_load((const u64*)(pb + kq * 32 + q * 2),
                                               __ATOMIC_RELAXED, __HIP_MEMORY_SCOPE_AGENT);
        bool ok = true;
        #pragma unroll
        for (int i = 0; i < 16; ++i)
          ok &= (((unsigned)wv[i]) >> 16) >= tgt;  // u64 pair written atomically: low tag suffices
        if (__all(ok)) break;
        __builtin_amdgcn_s_sleep(1);
      }

      // ---- unpack + MFMA (16 per wave), B from VGPRs ----
      #pragma unroll
      for (int kq = 0; kq < 4; ++kq) {
        union { unsigned u[4]; bf16x8 v; } a;
        #pragma unroll
        for (int q = 0; q < 4; ++q) {
          const u64 w2 = wv[kq * 4 + q];
          a.u[q] = ((unsigned)w2 & 0xffffu) | (((unsigned)(w2 >> 32)) << 16);
        }
        #pragma unroll
        for (int nf = 0; nf < 4; ++nf)
          acc[nf] = __builtin_amdgcn_mfma_f32_16x16x32_bf16(a.v, Bf[nf][kq], acc[nf], 0, 0, 0);
      }
    }

    // K-partials to LDS
    #pragma unroll
    for (int nf = 0; nf < 4; ++nf)
      *(f32x4*)&Red[k8][nf * 16 + l15][lk * 4] = acc[nf];
    __syncthreads();  // S1: partials visible

    // ---- reduce + xp + tanh -> tagged u64 col-pair stores (relaxed AGENT) ----
    #pragma unroll
    for (int r = 0; r < 2; ++r) {
      const int row = rg * 2 + r;
      float s = Red[0][rcol][row];
      #pragma unroll
      for (int q = 1; q < 8; ++q) s += Red[q][rcol][row];
      const float z = s + xpv[r];
      const float e = __expf(2.0f * z);
      const float hv = 1.0f - 2.0f / (e + 1.0f);   // tanh(z)
      if (t == NT - 1) out[(size_t)(r0 + row) * NU + gcol] = hv;
      const unsigned word = tagn | (unsigned)f2bf(hv);
      const unsigned pw = (unsigned)__shfl_xor((int)word, 1);
      if (!(lane & 1)) {
        const u64 dw = (u64)word | ((u64)pw << 32);
        __hip_atomic_store((u64*)(hn + (size_t)(r0 + row) * NU + gcol), dw,
                           __ATOMIC_RELAXED, __HIP_MEMORY_SCOPE_AGENT);
      }
    }
    __syncthreads();  // S2: Red reads done before next step's partial writes
  }
}

extern "C" void kernel_launch(void* const* d_in, const int* in_sizes, int n_in,
                              void* d_out, int out_size, void* d_ws, size_t ws_size,
                              hipStream_t stream) {
  (void)in_sizes; (void)n_in; (void)out_size;
  const float* inp  = (const float*)d_in[0];
  const float* Wx   = (const float*)d_in[1];
  const float* Wh   = (const float*)d_in[2];
  const float* bias = (const float*)d_in[3];
  float* out = (float*)d_out;

  unsigned* ws = (unsigned*)d_ws;                             // 4 KB control area
  unsigned* hw = (unsigned*)((char*)d_ws + 4096);             // 512 KB tagged h x2
  const size_t xp_off = 4096 + (size_t)2 * NB * NU * sizeof(unsigned);
  float* xp = (float*)((char*)d_ws + xp_off);
  const size_t avail = (ws_size > xp_off) ? ws_size - xp_off : 0;

  int Tc = 128;
  for (int cand = NT; cand >= 128; cand >>= 1)
    if ((size_t)NB * (size_t)cand * NU * sizeof(float) <= avail) { Tc = cand; break; }

  init_ws<<<dim3(128), dim3(256), 0, stream>>>(ws);

  for (int t0 = 0; t0 < NT; t0 += Tc) {
    gemm_xp<<<dim3(8, (NB * Tc) / 128), dim3(256), 0, stream>>>(inp, Wx, bias, xp, t0, Tc);
    scan_kernel<<<dim3(256), dim3(512), 0, stream>>>(Wh, xp, hw, out, ws, t0, Tc, t0 / Tc);
  }
}